// Round 5
// baseline (436.699 us; speedup 1.0000x reference)
//
#include <hip/hip_runtime.h>
#include <hip/hip_bf16.h>

typedef unsigned short ushort_t;
typedef __bf16 bf16x8 __attribute__((ext_vector_type(8)));
typedef float f32x4 __attribute__((ext_vector_type(4)));

#define N_TOK 2048
#define DH    1024
#define FF    512
#define SFF   2816
#define NE    16

#define BM 128
#define BN 64
#define BK 64
#define LDK 72   // 64 + 8 pad (ushorts); row = 144 B; 2-way bank alias = free

__device__ __forceinline__ ushort_t f2bf(float f) {
  unsigned int x = __float_as_uint(f);
  unsigned int lsb = (x >> 16) & 1u;
  x += 0x7fffu + lsb;            // RNE; finite inputs
  return (ushort_t)(x >> 16);
}

__device__ __forceinline__ uint4 cvt8v(const float4 a, const float4 b) {
  union { ushort_t u[8]; uint4 v; } r;
  r.u[0] = f2bf(a.x); r.u[1] = f2bf(a.y); r.u[2] = f2bf(a.z); r.u[3] = f2bf(a.w);
  r.u[4] = f2bf(b.x); r.u[5] = f2bf(b.y); r.u[6] = f2bf(b.z); r.u[7] = f2bf(b.w);
  return r.v;
}

__device__ __forceinline__ uint4 ld_cvt8(const float* __restrict__ p) {
  float4 a = *(const float4*)p;
  float4 b = *(const float4*)(p + 4);
  return cvt8v(a, b);
}

// ---------------- final epilogue: out = acc ----------------
__global__ void out_epilogue_kernel(const float4* __restrict__ acc, float4* __restrict__ out) {
  size_t i = (size_t)blockIdx.x * 256 + threadIdx.x;
  out[i] = acc[i];
}

// ---------------- router (fp32) + zero acc ----------------
__global__ void router_kernel(const float* __restrict__ X, const float* __restrict__ GW,
                              const float* __restrict__ SGW,
                              int* __restrict__ sel, float* __restrict__ wtk,
                              float* __restrict__ sgate, float4* __restrict__ accv) {
  // zero the 4 acc rows this block's 4 tokens own: 4*1024 floats = 1024 float4
  {
    size_t b0 = (size_t)blockIdx.x * 1024 + threadIdx.x;
    float4 z = make_float4(0.f, 0.f, 0.f, 0.f);
    accv[b0] = z; accv[b0 + 256] = z; accv[b0 + 512] = z; accv[b0 + 768] = z;
  }
  int wave = threadIdx.x >> 6, lane = threadIdx.x & 63;
  int n = blockIdx.x * 4 + wave;
  const float* x = X + (size_t)n * DH;
  int e = lane & 15, s = lane >> 4;
  const float* gw = GW + (size_t)e * DH;
  float lg = 0.f;
  for (int i = 0; i < 256; ++i) {
    int d = s * 256 + i;
    lg += x[d] * gw[d];
  }
  lg += __shfl_down(lg, 32);
  lg += __shfl_down(lg, 16);          // lanes 0..15 hold logits[e]

  float gd = 0.f;
  #pragma unroll
  for (int i = 0; i < 16; ++i) {
    int d = lane * 16 + i;
    gd += x[d] * SGW[d];
  }
  #pragma unroll
  for (int off = 32; off >= 1; off >>= 1) gd += __shfl_down(gd, off);

  float l[16];
  #pragma unroll
  for (int i = 0; i < 16; ++i) l[i] = __shfl(lg, i);

  if (lane == 0) {
    int i1 = 0; float v1 = l[0];
    #pragma unroll
    for (int i = 1; i < 16; ++i) if (l[i] > v1) { v1 = l[i]; i1 = i; }
    int i2 = -1; float v2 = -1e30f;
    #pragma unroll
    for (int i = 0; i < 16; ++i) { if (i == i1) continue; if (l[i] > v2) { v2 = l[i]; i2 = i; } }
    float p2 = __expf(v2 - v1);          // softmax denom cancels in renorm
    float inv = 1.f / (1.f + p2);
    sel[n * 2 + 0] = i1; sel[n * 2 + 1] = i2;
    wtk[n * 2 + 0] = inv; wtk[n * 2 + 1] = p2 * inv;
    sgate[n] = 1.f / (1.f + __expf(-gd));
  }
}

// ---------------- single-block scatter: compact per-expert token lists ----------------
__global__ void scatter_kernel(const int* __restrict__ sel, const float* __restrict__ wtk,
                               int* __restrict__ toks, float* __restrict__ wts,
                               int* __restrict__ offs) {
  __shared__ int cnt[NE], bas[NE];
  int t = threadIdx.x;
  if (t < NE) cnt[t] = 0;
  __syncthreads();
  for (int i = t; i < N_TOK * 2; i += 256) atomicAdd(&cnt[sel[i]], 1);
  __syncthreads();
  if (t == 0) {
    int s = 0;
    for (int e = 0; e < NE; ++e) { bas[e] = s; offs[e] = s; s += cnt[e]; }
    offs[NE] = s;
  }
  __syncthreads();
  if (t < NE) cnt[t] = 0;
  __syncthreads();
  for (int i = t; i < N_TOK * 2; i += 256) {
    int e = sel[i];
    int p = atomicAdd(&cnt[e], 1);
    int slot = bas[e] + p;
    toks[slot] = i >> 1;
    wts[slot]  = wtk[i];
  }
}

// ---------------- merged gate_up + SwiGLU (expert blocks [0,2048), shared [2048,2752)) ----------------
__global__ __launch_bounds__(256, 3) void gateup_kernel(
    const float* __restrict__ X, const float* __restrict__ WGU,
    const float* __restrict__ Bg, const float* __restrict__ Bu,
    ushort_t* __restrict__ HX, ushort_t* __restrict__ HS,
    const int* __restrict__ toks, const int* __restrict__ offs) {
  __shared__ __align__(16) ushort_t As[BM][LDK];
  __shared__ __align__(16) ushort_t Bgs[BN][LDK];
  __shared__ __align__(16) ushort_t Bus[BN][LDK];
  const int K = DH, NT = K / BK;

  int bid = blockIdx.x;
  int t = threadIdx.x;
  int wave = t >> 6, lane = t & 63;
  int wm = wave & 1, wn = wave >> 1;
  int qd = lane >> 4, l16 = lane & 15;
  int sr = t >> 3, sc = (t & 7) * 8;

  if (bid < 2048) {
    // ---------- expert path ----------
    int e = bid >> 7, rem = bid & 127;
    int n0 = (rem & 7) * BN, m0 = (rem >> 3) * BM;
    int base = offs[e], M = offs[e + 1] - base;
    if (m0 >= M) return;
    const float* W = WGU + (size_t)e * DH * (2 * FF);
    int tn = t & 63, tk = (t >> 6) * 16;

    const float* arow[4];
    #pragma unroll
    for (int p = 0; p < 4; ++p) {
      int m = m0 + sr + 32 * p;
      int mm = m < M ? m : (M - 1);
      arow[p] = X + (size_t)toks[base + mm] * K + sc;
    }
    const float* wkb = W + (size_t)tk * (2 * FF) + n0 + tn;

    uint4 ar[4];
    float bgr[16], bur[16];
    #pragma unroll
    for (int p = 0; p < 4; ++p) ar[p] = ld_cvt8(arow[p]);
    #pragma unroll
    for (int j = 0; j < 16; ++j) {
      bgr[j] = wkb[(size_t)j * (2 * FF)];
      bur[j] = wkb[(size_t)j * (2 * FF) + FF];
    }

    f32x4 accg[4][2], accu[4][2];
    #pragma unroll
    for (int i = 0; i < 4; ++i)
      #pragma unroll
      for (int j = 0; j < 2; ++j) {
        accg[i][j] = (f32x4){0.f, 0.f, 0.f, 0.f};
        accu[i][j] = (f32x4){0.f, 0.f, 0.f, 0.f};
      }

    for (int kt = 0; kt < NT; ++kt) {
      #pragma unroll
      for (int p = 0; p < 4; ++p)
        *(uint4*)&As[sr + 32 * p][sc] = ar[p];
      {
        union { ushort_t u[8]; uint4 v; } g0, g1, u0, u1;
        #pragma unroll
        for (int j = 0; j < 8; ++j) {
          g0.u[j] = f2bf(bgr[j]); g1.u[j] = f2bf(bgr[8 + j]);
          u0.u[j] = f2bf(bur[j]); u1.u[j] = f2bf(bur[8 + j]);
        }
        *(uint4*)&Bgs[tn][tk]     = g0.v;
        *(uint4*)&Bgs[tn][tk + 8] = g1.v;
        *(uint4*)&Bus[tn][tk]     = u0.v;
        *(uint4*)&Bus[tn][tk + 8] = u1.v;
      }
      __syncthreads();
      if (kt + 1 < NT) {
        int ko = (kt + 1) * BK;
        #pragma unroll
        for (int p = 0; p < 4; ++p) ar[p] = ld_cvt8(arow[p] + ko);
        const float* wk = wkb + (size_t)ko * (2 * FF);
        #pragma unroll
        for (int j = 0; j < 16; ++j) {
          bgr[j] = wk[(size_t)j * (2 * FF)];
          bur[j] = wk[(size_t)j * (2 * FF) + FF];
        }
      }
      #pragma unroll
      for (int ks = 0; ks < 2; ++ks) {
        int kk = ks * 32 + qd * 8;
        bf16x8 af[4], bgf[2], buf[2];
        #pragma unroll
        for (int i = 0; i < 4; ++i)
          af[i] = *(const bf16x8*)&As[wm * 64 + i * 16 + l16][kk];
        #pragma unroll
        for (int j = 0; j < 2; ++j) {
          bgf[j] = *(const bf16x8*)&Bgs[wn * 32 + j * 16 + l16][kk];
          buf[j] = *(const bf16x8*)&Bus[wn * 32 + j * 16 + l16][kk];
        }
        #pragma unroll
        for (int i = 0; i < 4; ++i)
          #pragma unroll
          for (int j = 0; j < 2; ++j) {
            accg[i][j] = __builtin_amdgcn_mfma_f32_16x16x32_bf16(af[i], bgf[j], accg[i][j], 0, 0, 0);
            accu[i][j] = __builtin_amdgcn_mfma_f32_16x16x32_bf16(af[i], buf[j], accu[i][j], 0, 0, 0);
          }
      }
      __syncthreads();
    }

    #pragma unroll
    for (int i = 0; i < 4; ++i)
      #pragma unroll
      for (int r = 0; r < 4; ++r) {
        int m = m0 + wm * 64 + i * 16 + qd * 4 + r;
        if (m >= M) continue;
        #pragma unroll
        for (int j = 0; j < 2; ++j) {
          float g = accg[i][j][r], u = accu[i][j][r];
          float h = g / (1.f + __expf(-g)) * u;
          int col = n0 + wn * 32 + j * 16 + l16;
          HX[(size_t)(base + m) * FF + col] = f2bf(h);
        }
      }
  } else {
    // ---------- shared path ----------
    unsigned s = bid - 2048;
    int n0 = (int)(s % 44u) * BN, m0 = (int)(s / 44u) * BM;

    const float* arow[4];
    const float *bgrow[2], *burow[2];
    #pragma unroll
    for (int p = 0; p < 4; ++p)
      arow[p] = X + (size_t)(m0 + sr + 32 * p) * K + sc;
    #pragma unroll
    for (int p = 0; p < 2; ++p) {
      bgrow[p] = Bg + (size_t)(n0 + sr + 32 * p) * K + sc;
      burow[p] = Bu + (size_t)(n0 + sr + 32 * p) * K + sc;
    }

    uint4 ar[4], bgr[2], bur[2];
    #pragma unroll
    for (int p = 0; p < 4; ++p) ar[p] = ld_cvt8(arow[p]);
    #pragma unroll
    for (int p = 0; p < 2; ++p) {
      bgr[p] = ld_cvt8(bgrow[p]);
      bur[p] = ld_cvt8(burow[p]);
    }

    f32x4 accg[4][2], accu[4][2];
    #pragma unroll
    for (int i = 0; i < 4; ++i)
      #pragma unroll
      for (int j = 0; j < 2; ++j) {
        accg[i][j] = (f32x4){0.f, 0.f, 0.f, 0.f};
        accu[i][j] = (f32x4){0.f, 0.f, 0.f, 0.f};
      }

    for (int kt = 0; kt < NT; ++kt) {
      #pragma unroll
      for (int p = 0; p < 4; ++p)
        *(uint4*)&As[sr + 32 * p][sc] = ar[p];
      #pragma unroll
      for (int p = 0; p < 2; ++p) {
        *(uint4*)&Bgs[sr + 32 * p][sc] = bgr[p];
        *(uint4*)&Bus[sr + 32 * p][sc] = bur[p];
      }
      __syncthreads();
      if (kt + 1 < NT) {
        int ko = (kt + 1) * BK;
        #pragma unroll
        for (int p = 0; p < 4; ++p) ar[p] = ld_cvt8(arow[p] + ko);
        #pragma unroll
        for (int p = 0; p < 2; ++p) {
          bgr[p] = ld_cvt8(bgrow[p] + ko);
          bur[p] = ld_cvt8(burow[p] + ko);
        }
      }
      #pragma unroll
      for (int ks = 0; ks < 2; ++ks) {
        int kk = ks * 32 + qd * 8;
        bf16x8 af[4], bgf[2], buf[2];
        #pragma unroll
        for (int i = 0; i < 4; ++i)
          af[i] = *(const bf16x8*)&As[wm * 64 + i * 16 + l16][kk];
        #pragma unroll
        for (int j = 0; j < 2; ++j) {
          bgf[j] = *(const bf16x8*)&Bgs[wn * 32 + j * 16 + l16][kk];
          buf[j] = *(const bf16x8*)&Bus[wn * 32 + j * 16 + l16][kk];
        }
        #pragma unroll
        for (int i = 0; i < 4; ++i)
          #pragma unroll
          for (int j = 0; j < 2; ++j) {
            accg[i][j] = __builtin_amdgcn_mfma_f32_16x16x32_bf16(af[i], bgf[j], accg[i][j], 0, 0, 0);
            accu[i][j] = __builtin_amdgcn_mfma_f32_16x16x32_bf16(af[i], buf[j], accu[i][j], 0, 0, 0);
          }
      }
      __syncthreads();
    }

    #pragma unroll
    for (int i = 0; i < 4; ++i)
      #pragma unroll
      for (int r = 0; r < 4; ++r) {
        int m = m0 + wm * 64 + i * 16 + qd * 4 + r;
        #pragma unroll
        for (int j = 0; j < 2; ++j) {
          float g = accg[i][j][r], u = accu[i][j][r];
          float h = g / (1.f + __expf(-g)) * u;
          int col = n0 + wn * 32 + j * 16 + l16;
          HS[(size_t)m * SFF + col] = f2bf(h);
        }
      }
  }
}

// ---------------- merged down (expert blocks [0,4096), shared split-K=2 [4096,4608)) ----------------
__global__ __launch_bounds__(256, 4) void down_kernel(
    const ushort_t* __restrict__ HX, const ushort_t* __restrict__ HS,
    const float* __restrict__ WDN, const float* __restrict__ SWD,
    float* __restrict__ acc, const int* __restrict__ toks,
    const float* __restrict__ wts, const int* __restrict__ offs,
    const float* __restrict__ sgate) {
  __shared__ __align__(16) ushort_t As[BM][LDK];
  __shared__ __align__(16) ushort_t Bs[BN][LDK];

  int bid = blockIdx.x;
  int t = threadIdx.x;
  int wave = t >> 6, lane = t & 63;
  int wm = wave & 1, wn = wave >> 1;
  int qd = lane >> 4, l16 = lane & 15;
  int sr = t >> 3, sc = (t & 7) * 8;

  if (bid < 4096) {
    // ---------- expert path: acc[tok] += w * (hx @ Wd) ----------
    int e = bid >> 8, rem = bid & 255;
    int n0 = (rem & 15) * BN, m0 = (rem >> 4) * BM;
    int base = offs[e], M = offs[e + 1] - base;
    if (m0 >= M) return;
    const int K = FF, NT = K / BK;
    const float* W = WDN + (size_t)e * FF * DH;
    const ushort_t* A = HX + (size_t)base * K;
    int tn = t & 63, tk = (t >> 6) * 16;

    const ushort_t* arow[4];
    #pragma unroll
    for (int p = 0; p < 4; ++p)
      arow[p] = A + (size_t)(m0 + sr + 32 * p) * K + sc;
    const float* wkb = W + (size_t)tk * DH + n0 + tn;

    uint4 ar[4];
    float br[16];
    #pragma unroll
    for (int p = 0; p < 4; ++p) ar[p] = *(const uint4*)(arow[p]);
    #pragma unroll
    for (int j = 0; j < 16; ++j) br[j] = wkb[(size_t)j * DH];

    f32x4 c[4][2];
    #pragma unroll
    for (int i = 0; i < 4; ++i)
      #pragma unroll
      for (int j = 0; j < 2; ++j) c[i][j] = (f32x4){0.f, 0.f, 0.f, 0.f};

    for (int kt = 0; kt < NT; ++kt) {
      #pragma unroll
      for (int p = 0; p < 4; ++p)
        *(uint4*)&As[sr + 32 * p][sc] = ar[p];
      {
        union { ushort_t u[8]; uint4 v; } b0, b1;
        #pragma unroll
        for (int j = 0; j < 8; ++j) { b0.u[j] = f2bf(br[j]); b1.u[j] = f2bf(br[8 + j]); }
        *(uint4*)&Bs[tn][tk]     = b0.v;
        *(uint4*)&Bs[tn][tk + 8] = b1.v;
      }
      __syncthreads();
      if (kt + 1 < NT) {
        int ko = (kt + 1) * BK;
        #pragma unroll
        for (int p = 0; p < 4; ++p) ar[p] = *(const uint4*)(arow[p] + ko);
        const float* wk = wkb + (size_t)ko * DH;
        #pragma unroll
        for (int j = 0; j < 16; ++j) br[j] = wk[(size_t)j * DH];
      }
      #pragma unroll
      for (int ks = 0; ks < 2; ++ks) {
        int kk = ks * 32 + qd * 8;
        bf16x8 af[4], bf[2];
        #pragma unroll
        for (int i = 0; i < 4; ++i)
          af[i] = *(const bf16x8*)&As[wm * 64 + i * 16 + l16][kk];
        #pragma unroll
        for (int j = 0; j < 2; ++j)
          bf[j] = *(const bf16x8*)&Bs[wn * 32 + j * 16 + l16][kk];
        #pragma unroll
        for (int i = 0; i < 4; ++i)
          #pragma unroll
          for (int j = 0; j < 2; ++j)
            c[i][j] = __builtin_amdgcn_mfma_f32_16x16x32_bf16(af[i], bf[j], c[i][j], 0, 0, 0);
      }
      __syncthreads();
    }

    #pragma unroll
    for (int i = 0; i < 4; ++i)
      #pragma unroll
      for (int r = 0; r < 4; ++r) {
        int m = m0 + wm * 64 + i * 16 + qd * 4 + r;
        if (m >= M) continue;
        int tok = toks[base + m];
        float w = wts[base + m];
        #pragma unroll
        for (int j = 0; j < 2; ++j) {
          int n = n0 + wn * 32 + j * 16 + l16;
          atomicAdd(&acc[(size_t)tok * DH + n], c[i][j][r] * w);
        }
      }
  } else {
    // ---------- shared path (split-K=2): acc += sg * (hs @ swd^T) ----------
    int s = bid - 4096;
    int kz = s >> 8, rem = s & 255;
    int n0 = (rem & 15) * BN, m0 = (rem >> 4) * BM;
    const int KC = SFF / 2, NT = KC / BK;   // 1408, 22
    int kb = kz * KC;

    const ushort_t* arow[4];
    const float* brow[2];
    #pragma unroll
    for (int p = 0; p < 4; ++p)
      arow[p] = HS + (size_t)(m0 + sr + 32 * p) * SFF + kb + sc;
    #pragma unroll
    for (int p = 0; p < 2; ++p)
      brow[p] = SWD + (size_t)(n0 + sr + 32 * p) * SFF + kb + sc;

    uint4 ar[4], br[2];
    #pragma unroll
    for (int p = 0; p < 4; ++p) ar[p] = *(const uint4*)(arow[p]);
    #pragma unroll
    for (int p = 0; p < 2; ++p) br[p] = ld_cvt8(brow[p]);

    f32x4 c[4][2];
    #pragma unroll
    for (int i = 0; i < 4; ++i)
      #pragma unroll
      for (int j = 0; j < 2; ++j) c[i][j] = (f32x4){0.f, 0.f, 0.f, 0.f};

    for (int kt = 0; kt < NT; ++kt) {
      #pragma unroll
      for (int p = 0; p < 4; ++p)
        *(uint4*)&As[sr + 32 * p][sc] = ar[p];
      #pragma unroll
      for (int p = 0; p < 2; ++p)
        *(uint4*)&Bs[sr + 32 * p][sc] = br[p];
      __syncthreads();
      if (kt + 1 < NT) {
        int ko = (kt + 1) * BK;
        #pragma unroll
        for (int p = 0; p < 4; ++p) ar[p] = *(const uint4*)(arow[p] + ko);
        #pragma unroll
        for (int p = 0; p < 2; ++p) br[p] = ld_cvt8(brow[p] + ko);
      }
      #pragma unroll
      for (int ks = 0; ks < 2; ++ks) {
        int kk = ks * 32 + qd * 8;
        bf16x8 af[4], bf[2];
        #pragma unroll
        for (int i = 0; i < 4; ++i)
          af[i] = *(const bf16x8*)&As[wm * 64 + i * 16 + l16][kk];
        #pragma unroll
        for (int j = 0; j < 2; ++j)
          bf[j] = *(const bf16x8*)&Bs[wn * 32 + j * 16 + l16][kk];
        #pragma unroll
        for (int i = 0; i < 4; ++i)
          #pragma unroll
          for (int j = 0; j < 2; ++j)
            c[i][j] = __builtin_amdgcn_mfma_f32_16x16x32_bf16(af[i], bf[j], c[i][j], 0, 0, 0);
      }
      __syncthreads();
    }

    #pragma unroll
    for (int i = 0; i < 4; ++i)
      #pragma unroll
      for (int r = 0; r < 4; ++r) {
        int m = m0 + wm * 64 + i * 16 + qd * 4 + r;
        float sg = sgate[m];
        #pragma unroll
        for (int j = 0; j < 2; ++j) {
          int n = n0 + wn * 32 + j * 16 + l16;
          atomicAdd(&acc[(size_t)m * DH + n], c[i][j][r] * sg);
        }
      }
  }
}

// ---------------- launcher ----------------
extern "C" void kernel_launch(void* const* d_in, const int* in_sizes, int n_in,
                              void* d_out, int out_size, void* d_ws, size_t ws_size,
                              hipStream_t stream) {
  const float* x    = (const float*)d_in[0];   // [2048,1024]
  const float* gw   = (const float*)d_in[1];   // [16,1024]
  const float* wgu  = (const float*)d_in[2];   // [16,1024,1024]
  const float* wdn  = (const float*)d_in[3];   // [16,512,1024]
  const float* swg  = (const float*)d_in[4];   // [2816,1024]
  const float* swu  = (const float*)d_in[5];   // [2816,1024]
  const float* swd  = (const float*)d_in[6];   // [1024,2816]
  const float* sgw  = (const float*)d_in[7];   // [1,1024]
  float* out = (float*)d_out;

  char* ws = (char*)d_ws;
  constexpr size_t OFF_ACC  = 0;                                       // 8,388,608 B
  constexpr size_t OFF_HS   = OFF_ACC + (size_t)N_TOK * DH * 4;        // +11,534,336
  constexpr size_t OFF_HX   = OFF_HS  + (size_t)N_TOK * SFF * 2;       // +4,325,376
  constexpr size_t OFF_TOK  = OFF_HX  + (size_t)4224 * FF * 2;
  constexpr size_t OFF_WTS  = OFF_TOK + 4224 * 4;
  constexpr size_t OFF_OFFS = OFF_WTS + 4224 * 4;
  constexpr size_t OFF_SEL  = OFF_OFFS + 32 * 4;
  constexpr size_t OFF_WTK  = OFF_SEL + 4096 * 4;
  constexpr size_t OFF_SG   = OFF_WTK + 4096 * 4;                      // end ~24.3 MB

  float*    acc   = (float*)(ws + OFF_ACC);
  ushort_t* hs    = (ushort_t*)(ws + OFF_HS);
  ushort_t* hx    = (ushort_t*)(ws + OFF_HX);
  int*      toks  = (int*)(ws + OFF_TOK);
  float*    wts   = (float*)(ws + OFF_WTS);
  int*      offs  = (int*)(ws + OFF_OFFS);
  int*      sel   = (int*)(ws + OFF_SEL);
  float*    wtk   = (float*)(ws + OFF_WTK);
  float*    sgate = (float*)(ws + OFF_SG);

  router_kernel<<<N_TOK / 4, 256, 0, stream>>>(x, gw, sgw, sel, wtk, sgate, (float4*)acc);
  scatter_kernel<<<1, 256, 0, stream>>>(sel, wtk, toks, wts, offs);
  // merged gate_up: expert 16e*16m*8n = 2048 blocks, shared 16m*44n = 704 blocks
  gateup_kernel<<<2048 + 704, 256, 0, stream>>>(x, wgu, swg, swu, hx, hs, toks, offs);
  // merged down: expert 16e*16m*16n = 4096 blocks, shared 2kz*16m*16n = 512 blocks
  down_kernel<<<4096 + 512, 256, 0, stream>>>(hx, hs, wdn, swd, acc, toks, wts, offs, sgate);
  out_epilogue_kernel<<<2048, 256, 0, stream>>>((const float4*)acc, (float4*)out);
}